// Round 1
// baseline (1358.521 us; speedup 1.0000x reference)
//
#include <hip/hip_runtime.h>

#define N_NODES 100000
#define N_EDGES 6400000
#define IN_CH 14
#define HID 16
#define OUT_CH 8

// ---------------------------------------------------------------------------
// Layer-1 scatter: 16 threads per edge. Lanes 0..13 atomically add x[src][c]
// into agg1[dst][c]; lane 14 bumps the degree counter. Consecutive lanes read
// consecutive channels of the same row -> coalesced 56B row fetch (x table is
// 5.6 MB, L2/LIC resident).
// ---------------------------------------------------------------------------
__global__ void scatter1_kernel(const float* __restrict__ x,
                                const int* __restrict__ src,
                                const int* __restrict__ dst,
                                float* __restrict__ agg1,
                                float* __restrict__ cnt) {
    long long gid = (long long)blockIdx.x * blockDim.x + threadIdx.x;
    long long e = gid >> 4;
    int c = (int)(gid & 15);
    if (e >= N_EDGES) return;
    int d = dst[e];
    if (c < IN_CH) {
        int s = src[e];
        atomicAdd(&agg1[(long long)d * IN_CH + c], x[(long long)s * IN_CH + c]);
    } else if (c == IN_CH) {
        atomicAdd(&cnt[d], 1.0f);
    }
}

// ---------------------------------------------------------------------------
// Layer-1 node update: h[n] = relu(W1_l @ mean + b1 + W1_r @ x[n])
// One thread per node; weights are tiny (16x14) and cache-resident.
// ---------------------------------------------------------------------------
__global__ void node1_kernel(const float* __restrict__ x,
                             const float* __restrict__ agg1,
                             const float* __restrict__ cnt,
                             const float* __restrict__ W_l,
                             const float* __restrict__ b,
                             const float* __restrict__ W_r,
                             float* __restrict__ h) {
    int n = blockIdx.x * blockDim.x + threadIdx.x;
    if (n >= N_NODES) return;
    float inv = 1.0f / fmaxf(cnt[n], 1.0f);
    float m[IN_CH], xr[IN_CH];
#pragma unroll
    for (int c = 0; c < IN_CH; ++c) {
        m[c] = agg1[(long long)n * IN_CH + c] * inv;
        xr[c] = x[(long long)n * IN_CH + c];
    }
#pragma unroll
    for (int o = 0; o < HID; ++o) {
        float acc = b[o];
#pragma unroll
        for (int c = 0; c < IN_CH; ++c)
            acc = fmaf(m[c], W_l[o * IN_CH + c], fmaf(xr[c], W_r[o * IN_CH + c], acc));
        h[(long long)n * HID + o] = fmaxf(acc, 0.0f);
    }
}

// ---------------------------------------------------------------------------
// Layer-2 scatter: 16 threads per edge, all 16 channels of h. Degree counts
// are reused from layer 1 (same graph).
// ---------------------------------------------------------------------------
__global__ void scatter2_kernel(const float* __restrict__ h,
                                const int* __restrict__ src,
                                const int* __restrict__ dst,
                                float* __restrict__ agg2) {
    long long gid = (long long)blockIdx.x * blockDim.x + threadIdx.x;
    long long e = gid >> 4;
    int c = (int)(gid & 15);
    if (e >= N_EDGES) return;
    int s = src[e];
    int d = dst[e];
    atomicAdd(&agg2[(long long)d * HID + c], h[(long long)s * HID + c]);
}

// ---------------------------------------------------------------------------
// Layer-2 node update: out[n] = W2_l @ mean2 + b2 + W2_r @ h[n]
// ---------------------------------------------------------------------------
__global__ void node2_kernel(const float* __restrict__ h,
                             const float* __restrict__ agg2,
                             const float* __restrict__ cnt,
                             const float* __restrict__ W_l,
                             const float* __restrict__ b,
                             const float* __restrict__ W_r,
                             float* __restrict__ out) {
    int n = blockIdx.x * blockDim.x + threadIdx.x;
    if (n >= N_NODES) return;
    float inv = 1.0f / fmaxf(cnt[n], 1.0f);
    float m[HID], hr[HID];
#pragma unroll
    for (int c = 0; c < HID; ++c) {
        m[c] = agg2[(long long)n * HID + c] * inv;
        hr[c] = h[(long long)n * HID + c];
    }
#pragma unroll
    for (int o = 0; o < OUT_CH; ++o) {
        float acc = b[o];
#pragma unroll
        for (int c = 0; c < HID; ++c)
            acc = fmaf(m[c], W_l[o * HID + c], fmaf(hr[c], W_r[o * HID + c], acc));
        out[(long long)n * OUT_CH + o] = acc;
    }
}

extern "C" void kernel_launch(void* const* d_in, const int* in_sizes, int n_in,
                              void* d_out, int out_size, void* d_ws, size_t ws_size,
                              hipStream_t stream) {
    const float* x    = (const float*)d_in[0];
    const int* eidx   = (const int*)d_in[1];   // [2, N_EDGES] int32
    // d_in[2] = edge_attr: unused by the reference
    const float* W1_l = (const float*)d_in[3];
    const float* b1   = (const float*)d_in[4];
    const float* W1_r = (const float*)d_in[5];
    const float* W2_l = (const float*)d_in[6];
    const float* b2   = (const float*)d_in[7];
    const float* W2_r = (const float*)d_in[8];
    float* out = (float*)d_out;

    const int* src = eidx;             // edge_index[0]
    const int* dst = eidx + N_EDGES;   // edge_index[1]

    // Workspace layout (floats):
    //   agg1: N_NODES*IN_CH = 1,400,000   @ 0
    //   cnt : N_NODES       =   100,000   @ 1,400,000
    //   agg2: N_NODES*HID   = 1,600,000   @ 1,500,000
    //   h   : N_NODES*HID   = 1,600,000   @ 3,100,000  (fully overwritten)
    float* ws   = (float*)d_ws;
    float* agg1 = ws;
    float* cnt  = ws + 1400000;
    float* agg2 = ws + 1500000;
    float* h    = ws + 3100000;

    // Zero the accumulators (agg1 + cnt + agg2 contiguous = 3.1M floats).
    hipMemsetAsync(ws, 0, 3100000 * sizeof(float), stream);

    const int B = 256;
    long long t1 = (long long)N_EDGES * 16;
    scatter1_kernel<<<(unsigned)((t1 + B - 1) / B), B, 0, stream>>>(x, src, dst, agg1, cnt);
    node1_kernel<<<(N_NODES + B - 1) / B, B, 0, stream>>>(x, agg1, cnt, W1_l, b1, W1_r, h);
    scatter2_kernel<<<(unsigned)((t1 + B - 1) / B), B, 0, stream>>>(h, src, dst, agg2);
    node2_kernel<<<(N_NODES + B - 1) / B, B, 0, stream>>>(h, agg2, cnt, W2_l, b2, W2_r, out);
}

// Round 2
// 1055.954 us; speedup vs baseline: 1.2865x; 1.2865x over previous
//
#include <hip/hip_runtime.h>

#define N_NODES 100000
#define N_EDGES 6400000
#define IN_CH 14
#define HID 16
#define OUT_CH 8

#define SCAN_BLK 256
#define N_SCAN_BLOCKS ((N_NODES + SCAN_BLK - 1) / SCAN_BLK)   // 391

// ---------------------------------------------------------------------------
// Pass 1: in-degree histogram. 6.4M int atomics (vs 90M fp32 in the scatter
// version); counts are reused by BOTH layers via rowptr.
// ---------------------------------------------------------------------------
__global__ void deg_kernel(const int* __restrict__ dst, int* __restrict__ deg) {
    int e = blockIdx.x * blockDim.x + threadIdx.x;
    if (e >= N_EDGES) return;
    atomicAdd(&deg[dst[e]], 1);
}

// ---------------------------------------------------------------------------
// Exclusive scan of deg -> rowptr, 3 small kernels.
// ---------------------------------------------------------------------------
__global__ void scan_blocksums(const int* __restrict__ deg, int* __restrict__ blockSums) {
    __shared__ int sdata[SCAN_BLK];
    int idx = blockIdx.x * SCAN_BLK + threadIdx.x;
    int v = (idx < N_NODES) ? deg[idx] : 0;
    sdata[threadIdx.x] = v;
    __syncthreads();
    for (int s = SCAN_BLK / 2; s > 0; s >>= 1) {
        if (threadIdx.x < s) sdata[threadIdx.x] += sdata[threadIdx.x + s];
        __syncthreads();
    }
    if (threadIdx.x == 0) blockSums[blockIdx.x] = sdata[0];
}

__global__ void scan_offsets(const int* __restrict__ blockSums, int* __restrict__ blockOff) {
    __shared__ int s[512];
    int t = threadIdx.x;
    int v = (t < N_SCAN_BLOCKS) ? blockSums[t] : 0;
    s[t] = v;
    __syncthreads();
    for (int d = 1; d < 512; d <<= 1) {
        int a = (t >= d) ? s[t - d] : 0;
        __syncthreads();
        s[t] += a;
        __syncthreads();
    }
    if (t < N_SCAN_BLOCKS) blockOff[t] = s[t] - v;   // exclusive
}

__global__ void scan_final(const int* __restrict__ deg, const int* __restrict__ blockOff,
                           int* __restrict__ rowptr) {
    __shared__ int s[SCAN_BLK];
    int t = threadIdx.x;
    int idx = blockIdx.x * SCAN_BLK + t;
    int v = (idx < N_NODES) ? deg[idx] : 0;
    s[t] = v;
    __syncthreads();
    for (int d = 1; d < SCAN_BLK; d <<= 1) {
        int a = (t >= d) ? s[t - d] : 0;
        __syncthreads();
        s[t] += a;
        __syncthreads();
    }
    if (idx < N_NODES) rowptr[idx] = blockOff[blockIdx.x] + s[t] - v;  // exclusive
    if (idx == N_NODES - 1) rowptr[N_NODES] = N_EDGES;
}

// ---------------------------------------------------------------------------
// Pass 2: bucket edges by dst (counting sort). Order within a bucket is
// arbitrary (fp32 sum reassociation is within threshold).
// ---------------------------------------------------------------------------
__global__ void fill_csr(const int* __restrict__ src, const int* __restrict__ dst,
                         const int* __restrict__ rowptr, int* __restrict__ fill,
                         int* __restrict__ csr) {
    int e = blockIdx.x * blockDim.x + threadIdx.x;
    if (e >= N_EDGES) return;
    int d = dst[e];
    int slot = atomicAdd(&fill[d], 1);
    csr[rowptr[d] + slot] = src[e];
}

// ---------------------------------------------------------------------------
// Layer 1 fused gather + linear + relu.
// 16 lanes per node: lane c accumulates channel c over the neighbor list
// (x row = 56B contiguous across lanes; csr[j] is a wave-broadcast load).
// LDS exchange stays within one wave (16-lane groups) -> no __syncthreads.
// ---------------------------------------------------------------------------
__global__ void gather1_kernel(const float* __restrict__ x,
                               const int* __restrict__ rowptr,
                               const int* __restrict__ csr,
                               const float* __restrict__ W_l,
                               const float* __restrict__ b,
                               const float* __restrict__ W_r,
                               float* __restrict__ h) {
    int gid = blockIdx.x * blockDim.x + threadIdx.x;
    int n = gid >> 4;
    int c = gid & 15;
    if (n >= N_NODES) return;
    int beg = rowptr[n], end = rowptr[n + 1];
    float acc = 0.0f;
    if (c < IN_CH) {
        for (int j = beg; j < end; ++j) {
            int s = csr[j];
            acc += x[s * IN_CH + c];
        }
    }
    float invd = 1.0f / fmaxf((float)(end - beg), 1.0f);
    float meanc = acc * invd;
    float xc = (c < IN_CH) ? x[n * IN_CH + c] : 0.0f;

    __shared__ float sm[16][17];
    __shared__ float sx[16][17];
    int g = threadIdx.x >> 4;          // group id within block (same wave)
    sm[g][c] = meanc;
    sx[g][c] = xc;
    // same-wave LDS RAW: compiler inserts lgkmcnt wait; no barrier needed

    float acc2 = b[c];                 // lane c computes output channel c (HID=16)
#pragma unroll
    for (int k = 0; k < IN_CH; ++k)
        acc2 = fmaf(sm[g][k], W_l[c * IN_CH + k], fmaf(sx[g][k], W_r[c * IN_CH + k], acc2));
    h[n * HID + c] = fmaxf(acc2, 0.0f);
}

// ---------------------------------------------------------------------------
// Layer 2 fused gather + linear. HID=16 channels, OUT_CH=8 outputs.
// ---------------------------------------------------------------------------
__global__ void gather2_kernel(const float* __restrict__ h,
                               const int* __restrict__ rowptr,
                               const int* __restrict__ csr,
                               const float* __restrict__ W_l,
                               const float* __restrict__ b,
                               const float* __restrict__ W_r,
                               float* __restrict__ out) {
    int gid = blockIdx.x * blockDim.x + threadIdx.x;
    int n = gid >> 4;
    int c = gid & 15;
    if (n >= N_NODES) return;
    int beg = rowptr[n], end = rowptr[n + 1];
    float acc = 0.0f;
    for (int j = beg; j < end; ++j) {
        int s = csr[j];
        acc += h[s * HID + c];
    }
    float invd = 1.0f / fmaxf((float)(end - beg), 1.0f);
    float meanc = acc * invd;
    float hc = h[n * HID + c];

    __shared__ float sm[16][17];
    __shared__ float sh[16][17];
    int g = threadIdx.x >> 4;
    sm[g][c] = meanc;
    sh[g][c] = hc;

    if (c < OUT_CH) {
        float acc2 = b[c];
#pragma unroll
        for (int k = 0; k < HID; ++k)
            acc2 = fmaf(sm[g][k], W_l[c * HID + k], fmaf(sh[g][k], W_r[c * HID + k], acc2));
        out[n * OUT_CH + c] = acc2;
    }
}

extern "C" void kernel_launch(void* const* d_in, const int* in_sizes, int n_in,
                              void* d_out, int out_size, void* d_ws, size_t ws_size,
                              hipStream_t stream) {
    const float* x    = (const float*)d_in[0];
    const int* eidx   = (const int*)d_in[1];   // [2, N_EDGES] int32
    const float* W1_l = (const float*)d_in[3];
    const float* b1   = (const float*)d_in[4];
    const float* W1_r = (const float*)d_in[5];
    const float* W2_l = (const float*)d_in[6];
    const float* b2   = (const float*)d_in[7];
    const float* W2_r = (const float*)d_in[8];
    float* out = (float*)d_out;

    const int* src = eidx;
    const int* dst = eidx + N_EDGES;

    // Workspace layout (4-byte elements):
    //   deg      @ 0          (100,000 ints)   - zeroed
    //   fill     @ 100,000    (100,000 ints)   - zeroed
    //   rowptr   @ 200,000    (100,001 ints)
    //   blockSums@ 300,008    (391 ints)
    //   blockOff @ 300,408    (391 ints)
    //   csr      @ 300,800    (6,400,000 ints)
    //   h        @ 6,700,800  (1,600,000 floats)
    // total ~8.3M elems = 33.2 MB
    int*   wsi       = (int*)d_ws;
    int*   deg       = wsi;
    int*   fill      = wsi + 100000;
    int*   rowptr    = wsi + 200000;
    int*   blockSums = wsi + 300008;
    int*   blockOff  = wsi + 300408;
    int*   csr       = wsi + 300800;
    float* h         = (float*)(wsi + 6700800);

    hipMemsetAsync(wsi, 0, 200000 * sizeof(int), stream);   // deg + fill

    const int B = 256;
    const int EB = (N_EDGES + B - 1) / B;                   // 25000 blocks

    deg_kernel<<<EB, B, 0, stream>>>(dst, deg);
    scan_blocksums<<<N_SCAN_BLOCKS, SCAN_BLK, 0, stream>>>(deg, blockSums);
    scan_offsets<<<1, 512, 0, stream>>>(blockSums, blockOff);
    scan_final<<<N_SCAN_BLOCKS, SCAN_BLK, 0, stream>>>(deg, blockOff, rowptr);
    fill_csr<<<EB, B, 0, stream>>>(src, dst, rowptr, fill, csr);

    const int NG = (N_NODES * 16 + B - 1) / B;              // 6250 blocks
    gather1_kernel<<<NG, B, 0, stream>>>(x, rowptr, csr, W1_l, b1, W1_r, h);
    gather2_kernel<<<NG, B, 0, stream>>>(h, rowptr, csr, W2_l, b2, W2_r, out);
}